// Round 3
// baseline (427.192 us; speedup 1.0000x reference)
//
#include <hip/hip_runtime.h>
#include <math.h>

#define BATCH 8
#define CH    256
#define HWPIX 4096
#define CQK_  32

typedef __bf16 bf16x8 __attribute__((ext_vector_type(8)));
typedef __bf16 bf16x4 __attribute__((ext_vector_type(4)));
typedef __bf16 bf16x2 __attribute__((ext_vector_type(2)));
typedef float  f32x4  __attribute__((ext_vector_type(4)));
typedef float  f32x16 __attribute__((ext_vector_type(16)));

#define FS_STR 68   // LDS transpose-tile row stride in bf16 (136 B: 8B-aligned)

// load a bf16x8 fragment from LDS as two 8B halves (rows only 8B-aligned)
static __device__ inline bf16x8 ld_frag(const __bf16* p) {
  bf16x4 lo = *(const bf16x4*)p;
  bf16x4 hi = *(const bf16x4*)(p + 4);
  return __builtin_shufflevector(lo, hi, 0, 1, 2, 3, 4, 5, 6, 7);
}

// load 8 consecutive fp32 from a W row, convert to bf16x8 fragment
static __device__ inline bf16x8 w_frag(const float* p) {
  const float4 a = *(const float4*)p;
  const float4 b = *(const float4*)(p + 4);
  bf16x8 r;
  r[0] = (__bf16)a.x; r[1] = (__bf16)a.y; r[2] = (__bf16)a.z; r[3] = (__bf16)a.w;
  r[4] = (__bf16)b.x; r[5] = (__bf16)b.y; r[6] = (__bf16)b.z; r[7] = (__bf16)b.w;
  return r;
}

// ---- Fused projections. grid (64 n-tiles, 3 modes, 8 b), block 256 = 4 waves.
// mode 0: Q -> qT[b][n][32] AND K -> kT'[b][n][32] (kT rows PERMUTED, see below)
// mode 1,2: V c-half (mode-1)*128 -> vv[b][c][hw]
//
// kT permutation: within each 32-key block, storage slot s holds true key
//   key(s) = 8*((s>>2)&1) + (s&3) + 4*((s>>3)&1) + 16*(s>>4)
// chosen so that in attn's swapped 32x32x16 score MFMA (D row map
// (reg&3)+8*(reg>>2)+4*(lane>>5), m74-verified), register reg at lane-half hi
// holds true key 8*hi + (reg&7) + 16*(reg>>3) — i.e. exp(Sv[reg]) is ALREADY
// in the AV B-fragment order (k = 8*hi + j). P never leaves the lane.
__global__ __launch_bounds__(256, 4) void proj_all(
    const float* __restrict__ f1, const float* __restrict__ f2,
    const float* __restrict__ f3,
    const float* __restrict__ wq, const float* __restrict__ bq,
    const float* __restrict__ wk, const float* __restrict__ bk,
    const float* __restrict__ wv, const float* __restrict__ bv,
    __bf16* __restrict__ qT, __bf16* __restrict__ kT, __bf16* __restrict__ vv)
{
  __shared__ __align__(16) __bf16 f_s[2][64 * FS_STR];  // [n][cin] transposed tiles
  const int t    = threadIdx.x;
  const int w    = __builtin_amdgcn_readfirstlane(t >> 6);
  const int lane = t & 63;
  const int q16  = lane & 15;
  const int quad = lane >> 4;
  const int b    = blockIdx.z;
  const int n0   = blockIdx.x * 64;
  const int mode = blockIdx.y;

  // staging helper: f[c0..+64)[n0..+64) -> dst[n][cin] bf16 (transposed)
  const int sn  = (t & 15) * 4;
  const int scp = (t >> 4) * 2;
#define STAGE(fb, c0, dst)                                                      \
  {                                                                             \
    _Pragma("unroll") for (int rr = 0; rr < 2; ++rr) {                          \
      const int c = rr * 32 + scp;                                              \
      const float4 a0 = *(const float4*)&(fb)[(size_t)((c0) + c) * HWPIX + sn]; \
      const float4 a1 = *(const float4*)&(fb)[(size_t)((c0) + c + 1) * HWPIX + sn]; \
      _Pragma("unroll") for (int i = 0; i < 4; ++i) {                           \
        bf16x2 pk;                                                              \
        pk[0] = (__bf16)((const float*)&a0)[i];                                 \
        pk[1] = (__bf16)((const float*)&a1)[i];                                 \
        *(bf16x2*)&(dst)[(sn + i) * FS_STR + c] = pk;                           \
      }                                                                         \
    }                                                                           \
  }

  if (mode == 0) {
    const float* f1b = f1 + (size_t)b * CH * HWPIX + n0;
    const float* f2b = f2 + (size_t)b * CH * HWPIX + n0;
    f32x4 accQ[2], accK[2];
#pragma unroll
    for (int i = 0; i < 2; ++i) {
      accQ[i] = (f32x4){0.f, 0.f, 0.f, 0.f};
      accK[i] = (f32x4){0.f, 0.f, 0.f, 0.f};
    }
    for (int c0 = 0; c0 < CH; c0 += 64) {
      STAGE(f1b, c0, f_s[0]);
      STAGE(f2b, c0, f_s[1]);
      __syncthreads();
      bf16x8 afQ[2], afK[2];
#pragma unroll
      for (int kh = 0; kh < 2; ++kh) {
        afQ[kh] = ld_frag(&f_s[0][(16 * w + q16) * FS_STR + 32 * kh + quad * 8]);
        afK[kh] = ld_frag(&f_s[1][(16 * w + q16) * FS_STR + 32 * kh + quad * 8]);
      }
#pragma unroll
      for (int ot = 0; ot < 2; ++ot) {
#pragma unroll
        for (int kh = 0; kh < 2; ++kh) {
          const bf16x8 wfq =
              w_frag(wq + (size_t)(16 * ot + q16) * CH + c0 + 32 * kh + quad * 8);
          accQ[ot] = __builtin_amdgcn_mfma_f32_16x16x32_bf16(afQ[kh], wfq, accQ[ot], 0, 0, 0);
          const bf16x8 wfk =
              w_frag(wk + (size_t)(16 * ot + q16) * CH + c0 + 32 * kh + quad * 8);
          accK[ot] = __builtin_amdgcn_mfma_f32_16x16x32_bf16(afK[kh], wfk, accK[ot], 0, 0, 0);
        }
      }
      __syncthreads();
    }
    const float bq0 = bq[q16], bq1 = bq[16 + q16];
    const float bk0 = bk[q16], bk1 = bk[16 + q16];
#pragma unroll
    for (int r = 0; r < 4; ++r) {
      // Q: natural row order
      const size_t qrow = (size_t)b * HWPIX + n0 + 16 * w + quad * 4 + r;
      qT[qrow * CQK_ + q16]      = (__bf16)(accQ[0][r] + bq0);
      qT[qrow * CQK_ + 16 + q16] = (__bf16)(accQ[1][r] + bq1);
      // K: permuted row order within each 32-key block (see header comment)
      const int m   = 16 * (w & 1) + 4 * quad + r;       // key within 32-block
      const int hik = (m >> 3) & 1;
      const int rr  = (m & 7) + 8 * (m >> 4);
      const int s   = (rr & 3) + 8 * (rr >> 2) + 4 * hik; // storage slot
      const size_t krow = (size_t)b * HWPIX + n0 + 32 * (w >> 1) + s;
      kT[krow * CQK_ + q16]      = (__bf16)(accK[0][r] + bk0);
      kT[krow * CQK_ + 16 + q16] = (__bf16)(accK[1][r] + bk1);
    }
  } else {
    const int cbase = (mode - 1) * 128;
    const float* f3b = f3 + (size_t)b * CH * HWPIX + n0;
    f32x4 acc[2][4];
#pragma unroll
    for (int ct = 0; ct < 2; ++ct)
#pragma unroll
      for (int nt = 0; nt < 4; ++nt) acc[ct][nt] = (f32x4){0.f, 0.f, 0.f, 0.f};

    for (int c0 = 0; c0 < CH; c0 += 64) {
      STAGE(f3b, c0, f_s[0]);
      __syncthreads();
      bf16x8 af[2][2];  // [ct][kh] : W rows (c)
#pragma unroll
      for (int ct = 0; ct < 2; ++ct)
#pragma unroll
        for (int kh = 0; kh < 2; ++kh)
          af[ct][kh] = w_frag(wv + (size_t)(cbase + 64 * ct + 16 * w + q16) * CH
                              + c0 + 32 * kh + quad * 8);
#pragma unroll
      for (int nt = 0; nt < 4; ++nt) {
#pragma unroll
        for (int kh = 0; kh < 2; ++kh) {
          const bf16x8 bfr = ld_frag(&f_s[0][(16 * nt + q16) * FS_STR + 32 * kh + quad * 8]);
#pragma unroll
          for (int ct = 0; ct < 2; ++ct)
            acc[ct][nt] = __builtin_amdgcn_mfma_f32_16x16x32_bf16(
                af[ct][kh], bfr, acc[ct][nt], 0, 0, 0);
        }
      }
      __syncthreads();
    }
#pragma unroll
    for (int ct = 0; ct < 2; ++ct) {
      const float4 bi = *(const float4*)&bv[cbase + 64 * ct + 16 * w + quad * 4];
#pragma unroll
      for (int nt = 0; nt < 4; ++nt) {
#pragma unroll
        for (int r = 0; r < 4; ++r) {
          const int c = cbase + 64 * ct + 16 * w + quad * 4 + r;
          vv[((size_t)b * CH + c) * HWPIX + n0 + 16 * nt + q16] =
              (__bf16)(acc[ct][nt][r] + ((const float*)&bi)[r]);
        }
      }
    }
  }
#undef STAGE
}

// ---- Barrier-free flash attention. grid 512: b = bx&7 (XCD-pinned),
// 64-q tile = bx>>3. Block = 4 INDEPENDENT waves (no LDS, no __syncthreads).
// Wave w: ch range [128*(w&1), +128), q range [tile*64 + 32*(w>>1), +32).
// Scores: SWAPPED mfma_32x32x16(K', Q) with kT's permuted row layout, so
// exp(Sv[reg]) at lane-half hi is directly the AV B-fragment element
// (k = 8*hi + j within a 16-key step). P stays in registers; scores are
// computed 2x (once per ch-half wave) — trans-pipe cost, no sync cost.
// K and V register-prefetched one 32-key block ahead (static double buffer).
__global__ __launch_bounds__(256, 2) void attn_kernel(
    const __bf16* __restrict__ qT, const __bf16* __restrict__ kT,
    const __bf16* __restrict__ vv, float* __restrict__ out)
{
  const int t    = threadIdx.x;
  const int w    = __builtin_amdgcn_readfirstlane(t >> 6);
  const int lane = t & 63;
  const int lq   = lane & 31;  // q column (scores/AV) | ch row (V) | k-slot row (K)
  const int hi   = lane >> 5;

  const int b  = blockIdx.x & 7;
  const int tl = blockIdx.x >> 3;
  const int qbase  = tl * 64 + (w >> 1) * 32;
  const int chbase = (w & 1) * 128;

  // K: row = kb*32 + lq (storage slot), col = 16m + 8hi + j
  const __bf16* kp = kT + (size_t)b * HWPIX * CQK_ + (size_t)lq * CQK_ + 8 * hi;
  // Q: row = qbase + lq, col = 16m + 8hi + j
  const __bf16* qp = qT + ((size_t)b * HWPIX + qbase + lq) * CQK_ + 8 * hi;
  // V: row = chbase + 32ct + lq, col = kb*32 + 16f + 8hi + j
  const __bf16* vp0 = vv + ((size_t)b * CH + chbase +  0 + lq) * HWPIX + 8 * hi;
  const __bf16* vp1 = vp0 + (size_t)32 * HWPIX;
  const __bf16* vp2 = vp0 + (size_t)64 * HWPIX;
  const __bf16* vp3 = vp0 + (size_t)96 * HWPIX;

  const bf16x8 qf0 = *(const bf16x8*)(qp);
  const bf16x8 qf1 = *(const bf16x8*)(qp + 16);

  f32x16 oacc[4];
#pragma unroll
  for (int ct = 0; ct < 4; ++ct)
#pragma unroll
    for (int r = 0; r < 16; ++r) oacc[ct][r] = 0.f;
  float Lp = 0.f;

  // prologue: K/V fragments for block 0
  bf16x8 kA0, kA1, kB0, kB1;
  bf16x8 vA[4][2], vB[4][2];
  kA0 = *(const bf16x8*)(kp);
  kA1 = *(const bf16x8*)(kp + 16);
  vA[0][0] = *(const bf16x8*)(vp0);      vA[0][1] = *(const bf16x8*)(vp0 + 16);
  vA[1][0] = *(const bf16x8*)(vp1);      vA[1][1] = *(const bf16x8*)(vp1 + 16);
  vA[2][0] = *(const bf16x8*)(vp2);      vA[2][1] = *(const bf16x8*)(vp2 + 16);
  vA[3][0] = *(const bf16x8*)(vp3);      vA[3][1] = *(const bf16x8*)(vp3 + 16);

  const f32x16 z16 = {0.f,0.f,0.f,0.f,0.f,0.f,0.f,0.f,
                      0.f,0.f,0.f,0.f,0.f,0.f,0.f,0.f};

#define STEP(KB, CK0, CK1, CV, NK0, NK1, NV)                                    \
  {                                                                             \
    const int kn = ((KB) + 1) & 127;                                            \
    /* prefetch K/V for block kn into the other buffer */                       \
    NK0 = *(const bf16x8*)(kp + (size_t)kn * 1024);                             \
    NK1 = *(const bf16x8*)(kp + (size_t)kn * 1024 + 16);                        \
    NV[0][0] = *(const bf16x8*)(vp0 + kn * 32);                                 \
    NV[0][1] = *(const bf16x8*)(vp0 + kn * 32 + 16);                            \
    NV[1][0] = *(const bf16x8*)(vp1 + kn * 32);                                 \
    NV[1][1] = *(const bf16x8*)(vp1 + kn * 32 + 16);                            \
    NV[2][0] = *(const bf16x8*)(vp2 + kn * 32);                                 \
    NV[2][1] = *(const bf16x8*)(vp2 + kn * 32 + 16);                            \
    NV[3][0] = *(const bf16x8*)(vp3 + kn * 32);                                 \
    NV[3][1] = *(const bf16x8*)(vp3 + kn * 32 + 16);                            \
    /* scores for block KB (c contracted in two 16-halves) */                   \
    f32x16 Sv = __builtin_amdgcn_mfma_f32_32x32x16_bf16(CK0, qf0, z16, 0, 0, 0);\
    Sv = __builtin_amdgcn_mfma_f32_32x32x16_bf16(CK1, qf1, Sv, 0, 0, 0);        \
    /* exp -> P fragments, already in B-operand order (kT row perm) */          \
    bf16x8 pf0, pf1;                                                            \
    _Pragma("unroll") for (int j = 0; j < 8; ++j) {                             \
      const float e = __expf(Sv[j]);                                            \
      Lp += e;                                                                  \
      pf0[j] = (__bf16)e;                                                       \
    }                                                                           \
    _Pragma("unroll") for (int j = 0; j < 8; ++j) {                             \
      const float e = __expf(Sv[8 + j]);                                        \
      Lp += e;                                                                  \
      pf1[j] = (__bf16)e;                                                       \
    }                                                                           \
    /* AV: two 16-key steps */                                                  \
    _Pragma("unroll") for (int ct = 0; ct < 4; ++ct) {                          \
      oacc[ct] = __builtin_amdgcn_mfma_f32_32x32x16_bf16(CV[ct][0], pf0,        \
                                                         oacc[ct], 0, 0, 0);    \
      oacc[ct] = __builtin_amdgcn_mfma_f32_32x32x16_bf16(CV[ct][1], pf1,        \
                                                         oacc[ct], 0, 0, 0);    \
    }                                                                           \
  }

  for (int kb = 0; kb < 128; kb += 2) {
    STEP(kb,     kA0, kA1, vA, kB0, kB1, vB);
    STEP(kb + 1, kB0, kB1, vB, kA0, kA1, vA);
  }
#undef STEP

  // row sum: other half of each 32-key block lives at lane^32
  Lp += __shfl_xor(Lp, 32);
  const float rinv = 1.0f / Lp;

  // D rows = ch offset (m74 layout); lane col = q
  float* ob = out + ((size_t)b * CH + chbase) * HWPIX + qbase + lq;
#pragma unroll
  for (int ct = 0; ct < 4; ++ct)
#pragma unroll
    for (int r = 0; r < 16; ++r) {
      const int ch = 32 * ct + (r & 3) + 8 * (r >> 2) + 4 * hi;
      ob[(size_t)ch * HWPIX] = oacc[ct][r] * rinv;
    }
}

extern "C" void kernel_launch(void* const* d_in, const int* in_sizes, int n_in,
                              void* d_out, int out_size, void* d_ws, size_t ws_size,
                              hipStream_t stream)
{
  const float* f1 = (const float*)d_in[0];
  const float* f2 = (const float*)d_in[1];
  const float* f3 = (const float*)d_in[2];
  const float* wq = (const float*)d_in[3];
  const float* bq = (const float*)d_in[4];
  const float* wk = (const float*)d_in[5];
  const float* bk = (const float*)d_in[6];
  const float* wv = (const float*)d_in[7];
  const float* bv = (const float*)d_in[8];
  float* outp = (float*)d_out;

  // workspace: qT [8][4096][32] | kT' [8][4096][32] (row-permuted) | v [8][256][4096]
  __bf16* qTw = (__bf16*)d_ws;
  __bf16* kTw = qTw + (size_t)BATCH * HWPIX * CQK_;
  __bf16* vw  = kTw + (size_t)BATCH * HWPIX * CQK_;

  proj_all<<<dim3(64, 3, 8), 256, 0, stream>>>(f1, f2, f3, wq, bq, wk, bk, wv, bv,
                                               qTw, kTw, vw);
  attn_kernel<<<dim3(512), 256, 0, stream>>>(qTw, kTw, vw, outp);
}

// Round 4
// 316.119 us; speedup vs baseline: 1.3514x; 1.3514x over previous
//
#include <hip/hip_runtime.h>
#include <math.h>

#define BATCH 8
#define CH    256
#define HWPIX 4096
#define CQK_  32

typedef __bf16 bf16x8 __attribute__((ext_vector_type(8)));
typedef __bf16 bf16x4 __attribute__((ext_vector_type(4)));
typedef __bf16 bf16x2 __attribute__((ext_vector_type(2)));
typedef float  f32x4  __attribute__((ext_vector_type(4)));

#define FS_STR 68   // LDS transpose-tile row stride in bf16 (136 B: 8B-aligned)

// load a bf16x8 fragment from LDS as two 8B halves (rows only 8B-aligned)
static __device__ inline bf16x8 ld_frag(const __bf16* p) {
  bf16x4 lo = *(const bf16x4*)p;
  bf16x4 hi = *(const bf16x4*)(p + 4);
  return __builtin_shufflevector(lo, hi, 0, 1, 2, 3, 4, 5, 6, 7);
}

// load 8 consecutive fp32 from a W row, convert to bf16x8 fragment
static __device__ inline bf16x8 w_frag(const float* p) {
  const float4 a = *(const float4*)p;
  const float4 b = *(const float4*)(p + 4);
  bf16x8 r;
  r[0] = (__bf16)a.x; r[1] = (__bf16)a.y; r[2] = (__bf16)a.z; r[3] = (__bf16)a.w;
  r[4] = (__bf16)b.x; r[5] = (__bf16)b.y; r[6] = (__bf16)b.z; r[7] = (__bf16)b.w;
  return r;
}

// ---- Fused projections. grid (64 n-tiles, 3 modes, 8 b), block 256 = 4 waves.
// mode 0: Q -> qT[b][n][32] AND K -> kT[b][n][32] (both staged)
// mode 1,2: V c-half (mode-1)*128 -> vv[b][c][hw]
// T14 async-STAGE: global loads for c-iter i+1 are issued BEFORE the compute
// phase of c-iter i (latency hidden under ld_frag/w_frag/MFMA); the regs are
// written to LDS only after the next barrier. Removes the per-iter
// "load -> drain -> write -> compute" serialization of the old STAGE.
__global__ __launch_bounds__(256, 4) void proj_all(
    const float* __restrict__ f1, const float* __restrict__ f2,
    const float* __restrict__ f3,
    const float* __restrict__ wq, const float* __restrict__ bq,
    const float* __restrict__ wk, const float* __restrict__ bk,
    const float* __restrict__ wv, const float* __restrict__ bv,
    __bf16* __restrict__ qT, __bf16* __restrict__ kT, __bf16* __restrict__ vv)
{
  __shared__ __align__(16) __bf16 f_s[2][64 * FS_STR];  // [n][cin] transposed tiles
  const int t    = threadIdx.x;
  const int w    = __builtin_amdgcn_readfirstlane(t >> 6);
  const int lane = t & 63;
  const int q16  = lane & 15;
  const int quad = lane >> 4;
  const int b    = blockIdx.z;
  const int n0   = blockIdx.x * 64;
  const int mode = blockIdx.y;

  // staging helpers: f[c0..+64)[n0..+64) -> regs -> dst[n][cin] bf16 (transposed)
  const int sn  = (t & 15) * 4;
  const int scp = (t >> 4) * 2;
#define STAGE_LOAD(fb, c0, reg)                                                  \
  {                                                                              \
    _Pragma("unroll") for (int rr = 0; rr < 2; ++rr) {                           \
      const int c = rr * 32 + scp;                                               \
      reg[2 * rr + 0] = *(const float4*)&(fb)[(size_t)((c0) + c) * HWPIX + sn];  \
      reg[2 * rr + 1] = *(const float4*)&(fb)[(size_t)((c0) + c + 1) * HWPIX + sn]; \
    }                                                                            \
  }
#define STAGE_WRITE(reg, dst)                                                    \
  {                                                                              \
    _Pragma("unroll") for (int rr = 0; rr < 2; ++rr) {                           \
      const int c = rr * 32 + scp;                                               \
      _Pragma("unroll") for (int i = 0; i < 4; ++i) {                            \
        bf16x2 pk;                                                               \
        pk[0] = (__bf16)((const float*)&reg[2 * rr + 0])[i];                     \
        pk[1] = (__bf16)((const float*)&reg[2 * rr + 1])[i];                     \
        *(bf16x2*)&(dst)[(sn + i) * FS_STR + c] = pk;                            \
      }                                                                          \
    }                                                                            \
  }

  if (mode == 0) {
    const float* f1b = f1 + (size_t)b * CH * HWPIX + n0;
    const float* f2b = f2 + (size_t)b * CH * HWPIX + n0;
    f32x4 accQ[2], accK[2];
#pragma unroll
    for (int i = 0; i < 2; ++i) {
      accQ[i] = (f32x4){0.f, 0.f, 0.f, 0.f};
      accK[i] = (f32x4){0.f, 0.f, 0.f, 0.f};
    }
    float4 rQ[4], rK[4];
    STAGE_LOAD(f1b, 0, rQ);
    STAGE_LOAD(f2b, 0, rK);
    for (int c0 = 0; c0 < CH; c0 += 64) {
      __syncthreads();  // previous iter's readers done; LDS reusable
      STAGE_WRITE(rQ, f_s[0]);
      STAGE_WRITE(rK, f_s[1]);
      __syncthreads();
      if (c0 < CH - 64) {  // prefetch next tile; latency hidden under compute
        STAGE_LOAD(f1b, c0 + 64, rQ);
        STAGE_LOAD(f2b, c0 + 64, rK);
      }
      bf16x8 afQ[2], afK[2];
#pragma unroll
      for (int kh = 0; kh < 2; ++kh) {
        afQ[kh] = ld_frag(&f_s[0][(16 * w + q16) * FS_STR + 32 * kh + quad * 8]);
        afK[kh] = ld_frag(&f_s[1][(16 * w + q16) * FS_STR + 32 * kh + quad * 8]);
      }
#pragma unroll
      for (int ot = 0; ot < 2; ++ot) {
#pragma unroll
        for (int kh = 0; kh < 2; ++kh) {
          const bf16x8 wfq =
              w_frag(wq + (size_t)(16 * ot + q16) * CH + c0 + 32 * kh + quad * 8);
          accQ[ot] = __builtin_amdgcn_mfma_f32_16x16x32_bf16(afQ[kh], wfq, accQ[ot], 0, 0, 0);
          const bf16x8 wfk =
              w_frag(wk + (size_t)(16 * ot + q16) * CH + c0 + 32 * kh + quad * 8);
          accK[ot] = __builtin_amdgcn_mfma_f32_16x16x32_bf16(afK[kh], wfk, accK[ot], 0, 0, 0);
        }
      }
    }
    const float bq0 = bq[q16], bq1 = bq[16 + q16];
    const float bk0 = bk[q16], bk1 = bk[16 + q16];
#pragma unroll
    for (int r = 0; r < 4; ++r) {
      const size_t row = (size_t)b * HWPIX + n0 + 16 * w + quad * 4 + r;
      qT[row * CQK_ + q16]      = (__bf16)(accQ[0][r] + bq0);
      qT[row * CQK_ + 16 + q16] = (__bf16)(accQ[1][r] + bq1);
      kT[row * CQK_ + q16]      = (__bf16)(accK[0][r] + bk0);
      kT[row * CQK_ + 16 + q16] = (__bf16)(accK[1][r] + bk1);
    }
  } else {
    const int cbase = (mode - 1) * 128;
    const float* f3b = f3 + (size_t)b * CH * HWPIX + n0;
    f32x4 acc[2][4];
#pragma unroll
    for (int ct = 0; ct < 2; ++ct)
#pragma unroll
      for (int nt = 0; nt < 4; ++nt) acc[ct][nt] = (f32x4){0.f, 0.f, 0.f, 0.f};

    float4 rV[4];
    STAGE_LOAD(f3b, 0, rV);
    for (int c0 = 0; c0 < CH; c0 += 64) {
      __syncthreads();
      STAGE_WRITE(rV, f_s[0]);
      __syncthreads();
      if (c0 < CH - 64) STAGE_LOAD(f3b, c0 + 64, rV);
      bf16x8 af[2][2];  // [ct][kh] : W rows (c)
#pragma unroll
      for (int ct = 0; ct < 2; ++ct)
#pragma unroll
        for (int kh = 0; kh < 2; ++kh)
          af[ct][kh] = w_frag(wv + (size_t)(cbase + 64 * ct + 16 * w + q16) * CH
                              + c0 + 32 * kh + quad * 8);
#pragma unroll
      for (int nt = 0; nt < 4; ++nt) {
#pragma unroll
        for (int kh = 0; kh < 2; ++kh) {
          const bf16x8 bfr = ld_frag(&f_s[0][(16 * nt + q16) * FS_STR + 32 * kh + quad * 8]);
#pragma unroll
          for (int ct = 0; ct < 2; ++ct)
            acc[ct][nt] = __builtin_amdgcn_mfma_f32_16x16x32_bf16(
                af[ct][kh], bfr, acc[ct][nt], 0, 0, 0);
        }
      }
    }
#pragma unroll
    for (int ct = 0; ct < 2; ++ct) {
      const float4 bi = *(const float4*)&bv[cbase + 64 * ct + 16 * w + quad * 4];
#pragma unroll
      for (int nt = 0; nt < 4; ++nt) {
#pragma unroll
        for (int r = 0; r < 4; ++r) {
          const int c = cbase + 64 * ct + 16 * w + quad * 4 + r;
          vv[((size_t)b * CH + c) * HWPIX + n0 + 16 * nt + q16] =
              (__bf16)(acc[ct][nt][r] + ((const float*)&bi)[r]);
        }
      }
    }
  }
#undef STAGE_LOAD
#undef STAGE_WRITE
}

// ---- Pipelined flash attention (R1 structure, best measured: 164 us).
// 8 waves/block (512 thr). grid 512: b = bx&7 (XCD-pinned), q-tile = bx>>3.
// Scores: wave w owns q rows [16*(w&3), +16) x m half (w>>2)*32, SWAPPED mfma(K,Q).
// AV: wave w owns output channels [32w, +32).
// P tile: [64 q][64 m] bf16, 128 B rows, byte ^= ((q16&7)<<4) XOR swizzle.
__global__ __launch_bounds__(512, 4) void attn_kernel(
    const __bf16* __restrict__ qT, const __bf16* __restrict__ kT,
    const __bf16* __restrict__ vv, float* __restrict__ out)
{
  __shared__ __align__(16) __bf16 p_s[2][64 * 64];  // [q][m], stride 64 bf16 = 128 B
  __shared__ float L_s[2][64];

  const int t    = threadIdx.x;
  const int w    = __builtin_amdgcn_readfirstlane(t >> 6);
  const int lane = t & 63;
  const int q16  = lane & 15;
  const int quad = lane >> 4;
  const int qb   = w & 3;   // score q-block (16 rows)
  const int hb   = w >> 2;  // score m-half (32 of 64 keys)
  const int swz  = (q16 & 7) << 4;

  const int b  = blockIdx.x & 7;
  const int q0 = (blockIdx.x >> 3) * 64;

  const __bf16* kTb = kT + (size_t)b * HWPIX * CQK_;
  // lane offset within a 64-key K tile: key = 32*hb + 16*mt + q16, ck = quad*8..+8
  const size_t koff = (size_t)(32 * hb + q16) * CQK_ + quad * 8;

  // running V pointers (advance 64 keys = 128 B per iter); ch = 32w + 16ct + q16
  const __bf16* vp[2];
#pragma unroll
  for (int ct = 0; ct < 2; ++ct)
    vp[ct] = vv + ((size_t)b * CH + 32 * w + 16 * ct + q16) * HWPIX + quad * 8;

  // Q fragment: q row = q0 + 16*qb + q16 (B-operand in swapped scores)
  const bf16x8 qfrag =
      *(const bf16x8*)(qT + ((size_t)b * HWPIX + q0 + 16 * qb + q16) * CQK_ + quad * 8);

  f32x4 oacc[2][4];
#pragma unroll
  for (int i = 0; i < 2; ++i)
#pragma unroll
    for (int j = 0; j < 4; ++j)
      oacc[i][j] = (f32x4){0.f, 0.f, 0.f, 0.f};
  float Lp = 0.f;  // lane-local partial row-sum (q row 16qb+q16, m-half hb)

  // ---- prologue: scores tile 0 -> p_s[0]; kf <- tile 1
  bf16x8 kf[2];
#pragma unroll
  for (int mt = 0; mt < 2; ++mt)
    kf[mt] = *(const bf16x8*)(kTb + koff + mt * 512);
  {
    f32x4 Sv[2];
#pragma unroll
    for (int mt = 0; mt < 2; ++mt)
      Sv[mt] = __builtin_amdgcn_mfma_f32_16x16x32_bf16(
          kf[mt], qfrag, (f32x4){0.f, 0.f, 0.f, 0.f}, 0, 0, 0);
    const __bf16* kb1 = kTb + 64 * CQK_;
#pragma unroll
    for (int mt = 0; mt < 2; ++mt)
      kf[mt] = *(const bf16x8*)(kb1 + koff + mt * 512);
    char* pw = (char*)p_s[0] + (16 * qb + q16) * 128;
#pragma unroll
    for (int mt = 0; mt < 2; ++mt) {
      bf16x4 pk;
#pragma unroll
      for (int r = 0; r < 4; ++r) {
        const float e = __expf(Sv[mt][r]);  // key = 32hb + 16mt + 4quad + r
        Lp += e;
        pk[r] = (__bf16)e;
      }
      *(bf16x4*)(pw + ((64 * hb + 32 * mt + 8 * quad) ^ swz)) = pk;
    }
  }
  __syncthreads();

  // ---- main loop: iter i does AV for tile i, scores+exp for tile i+1
  for (int i = 0; i < 64; ++i) {
    // V fragments for tile i (issued first; consumed after score/exp phase)
    bf16x8 vf[2][2];
#pragma unroll
    for (int ct = 0; ct < 2; ++ct)
#pragma unroll
      for (int mh = 0; mh < 2; ++mh)
        vf[ct][mh] = *(const bf16x8*)(vp[ct] + mh * 32);

    // P fragments for tile i (swizzled reads; all 64 q rows)
    const char* pb = (const char*)p_s[i & 1];
    bf16x8 pf[4][2];
#pragma unroll
    for (int nt = 0; nt < 4; ++nt)
#pragma unroll
      for (int mh = 0; mh < 2; ++mh)
        pf[nt][mh] = *(const bf16x8*)(pb + (16 * nt + q16) * 128
                                      + ((64 * mh + 16 * quad) ^ swz));

    if (i < 63) {
      // scores for tile i+1 (kf prefetched last iter), swapped operands
      f32x4 Sv[2];
#pragma unroll
      for (int mt = 0; mt < 2; ++mt)
        Sv[mt] = __builtin_amdgcn_mfma_f32_16x16x32_bf16(
            kf[mt], qfrag, (f32x4){0.f, 0.f, 0.f, 0.f}, 0, 0, 0);
      // prefetch kf for tile i+2
      const __bf16* kb2 = kTb + (size_t)((i + 2) & 63) * (64 * CQK_);
#pragma unroll
      for (int mt = 0; mt < 2; ++mt)
        kf[mt] = *(const bf16x8*)(kb2 + koff + mt * 512);
      // exp + packed b64 write of P[i+1] into the other buffer
      char* pw = (char*)p_s[(i + 1) & 1] + (16 * qb + q16) * 128;
#pragma unroll
      for (int mt = 0; mt < 2; ++mt) {
        bf16x4 pk;
#pragma unroll
        for (int r = 0; r < 4; ++r) {
          const float e = __expf(Sv[mt][r]);
          Lp += e;
          pk[r] = (__bf16)e;
        }
        *(bf16x4*)(pw + ((64 * hb + 32 * mt + 8 * quad) ^ swz)) = pk;
      }
    }

    // AV for tile i: O[ch = 32w+16ct+...][q = 16nt+...] += V * P
#pragma unroll
    for (int ct = 0; ct < 2; ++ct)
#pragma unroll
      for (int nt = 0; nt < 4; ++nt)
#pragma unroll
        for (int mh = 0; mh < 2; ++mh)
          oacc[ct][nt] = __builtin_amdgcn_mfma_f32_16x16x32_bf16(
              vf[ct][mh], pf[nt][mh], oacc[ct][nt], 0, 0, 0);

#pragma unroll
    for (int ct = 0; ct < 2; ++ct) vp[ct] += 64;
    __syncthreads();
  }

  // ---- finalize L: lane-local partial -> sum over the 4 quads (same q16)
  Lp += __shfl_xor(Lp, 16);
  Lp += __shfl_xor(Lp, 32);
  if (quad == 0) L_s[hb][16 * qb + q16] = Lp;
  __syncthreads();

  float rinv[4];
#pragma unroll
  for (int nt = 0; nt < 4; ++nt)
    rinv[nt] = 1.0f / (L_s[0][16 * nt + q16] + L_s[1][16 * nt + q16]);

  float* ob = out + ((size_t)b * CH + 32 * w) * HWPIX + q0;
#pragma unroll
  for (int ct = 0; ct < 2; ++ct)
#pragma unroll
    for (int r = 0; r < 4; ++r)
#pragma unroll
      for (int nt = 0; nt < 4; ++nt)
        ob[(size_t)(16 * ct + quad * 4 + r) * HWPIX + 16 * nt + q16] =
            oacc[ct][nt][r] * rinv[nt];
}

extern "C" void kernel_launch(void* const* d_in, const int* in_sizes, int n_in,
                              void* d_out, int out_size, void* d_ws, size_t ws_size,
                              hipStream_t stream)
{
  const float* f1 = (const float*)d_in[0];
  const float* f2 = (const float*)d_in[1];
  const float* f3 = (const float*)d_in[2];
  const float* wq = (const float*)d_in[3];
  const float* bq = (const float*)d_in[4];
  const float* wk = (const float*)d_in[5];
  const float* bk = (const float*)d_in[6];
  const float* wv = (const float*)d_in[7];
  const float* bv = (const float*)d_in[8];
  float* outp = (float*)d_out;

  // workspace: qT [8][4096][32] | kT [8][4096][32] | v [8][256][4096]  (bf16, 20 MB)
  __bf16* qTw = (__bf16*)d_ws;
  __bf16* kTw = qTw + (size_t)BATCH * HWPIX * CQK_;
  __bf16* vw  = kTw + (size_t)BATCH * HWPIX * CQK_;

  proj_all<<<dim3(64, 3, 8), 256, 0, stream>>>(f1, f2, f3, wq, bq, wk, bk, wv, bv,
                                               qTw, kTw, vw);
  attn_kernel<<<dim3(512), 512, 0, stream>>>(qTw, kTw, vw, outp);
}